// Round 1
// baseline (800.623 us; speedup 1.0000x reference)
//
#include <hip/hip_runtime.h>

#define N_NODES 50000
#define N_EDGES 800000
#define CH 128
#define TR 32   // rows per GEMM block

// ---- degree count: one thread per edge, atomic int add ----
__global__ __launch_bounds__(256) void k_deg(const int* __restrict__ rowv,
                                             int* __restrict__ deg) {
    int e = blockIdx.x * 256 + threadIdx.x;
    if (e < N_EDGES) atomicAdd(&deg[rowv[e]], 1);
}

// ---- dinv = rsqrt(max(deg,1)) ----
__global__ __launch_bounds__(256) void k_dinv(const int* __restrict__ deg,
                                              float* __restrict__ dinv) {
    int i = blockIdx.x * 256 + threadIdx.x;
    if (i < N_NODES) {
        int d = deg[i];
        dinv[i] = rsqrtf((float)(d > 0 ? d : 1));
    }
}

// ---- edge scatter: one wave (64 lanes) per edge, 2 channels/lane ----
// agg[row][c] += x[col][c] * dinv[row]*dinv[col]
__global__ __launch_bounds__(256) void k_scatter(const int* __restrict__ rowv,
                                                 const int* __restrict__ colv,
                                                 const float* __restrict__ dinv,
                                                 const float* __restrict__ x,
                                                 float* __restrict__ agg) {
    int gid = blockIdx.x * 256 + threadIdx.x;
    int e = gid >> 6;          // one edge per wave
    int lane = threadIdx.x & 63;
    if (e >= N_EDGES) return;
    int r = rowv[e];           // wave-uniform broadcast load
    int c = colv[e];
    float coef = dinv[r] * dinv[c];
    float2 v = *(const float2*)(x + (size_t)c * CH + 2 * lane);  // coalesced 512B gather
    float* dst = agg + (size_t)r * CH + 2 * lane;
    atomicAdd(dst,     v.x * coef);
    atomicAdd(dst + 1, v.y * coef);
}

// ---- in-place GEMM: io (N x 128, holds agg) -> io = io @ W (128 x 128) ----
// One block per TR rows. W staged in 64KB LDS, agg tile in LDS, 4x4 reg tile.
__global__ __launch_bounds__(256) void k_gemm(float* __restrict__ io,
                                              const float* __restrict__ W) {
    __shared__ float sW[CH * CH];   // 64 KB
    __shared__ float sA[TR * CH];   // 16 KB
    int t = threadIdx.x;

    const float4* W4 = (const float4*)W;
    float4* sW4 = (float4*)sW;
    #pragma unroll 4
    for (int i = t; i < CH * CH / 4; i += 256) sW4[i] = W4[i];

    int row0 = blockIdx.x * TR;
    int rows = N_NODES - row0; if (rows > TR) rows = TR;
    float4* sA4 = (float4*)sA;
    const float4* A4 = (const float4*)(io + (size_t)row0 * CH);
    for (int i = t; i < TR * CH / 4; i += 256) {
        int r = i >> 5;  // 32 float4 per row
        sA4[i] = (r < rows) ? A4[i] : make_float4(0.f, 0.f, 0.f, 0.f);
    }
    __syncthreads();

    // thread computes 4 rows x 4 cols: rows 4*(t>>5), cols 4*(t&31)
    int r0 = (t >> 5) * 4;
    int c0 = (t & 31) * 4;
    float acc[4][4] = {};
    for (int k = 0; k < CH; ++k) {
        float4 b = *(const float4*)&sW[k * CH + c0];
        #pragma unroll
        for (int i = 0; i < 4; ++i) {
            float a = sA[(r0 + i) * CH + k];   // broadcast within row-group
            acc[i][0] = fmaf(a, b.x, acc[i][0]);
            acc[i][1] = fmaf(a, b.y, acc[i][1]);
            acc[i][2] = fmaf(a, b.z, acc[i][2]);
            acc[i][3] = fmaf(a, b.w, acc[i][3]);
        }
    }
    // in-place safe: this block's rows fully captured in sA before barrier
    #pragma unroll
    for (int i = 0; i < 4; ++i) {
        if (r0 + i < rows) {
            *(float4*)(io + (size_t)(row0 + r0 + i) * CH + c0) =
                make_float4(acc[i][0], acc[i][1], acc[i][2], acc[i][3]);
        }
    }
}

extern "C" void kernel_launch(void* const* d_in, const int* in_sizes, int n_in,
                              void* d_out, int out_size, void* d_ws, size_t ws_size,
                              hipStream_t stream) {
    const float* x = (const float*)d_in[0];
    const float* W = (const float*)d_in[1];
    const int* edge = (const int*)d_in[2];
    const int* rowv = edge;            // edge_index[0][:]
    const int* colv = edge + N_EDGES;  // edge_index[1][:]
    float* out = (float*)d_out;

    int*   deg  = (int*)d_ws;
    float* dinv = (float*)((char*)d_ws + (size_t)N_NODES * sizeof(int));

    // zero accumulator (d_out re-poisoned to 0xAA before every launch) + deg
    hipMemsetAsync(out, 0, (size_t)N_NODES * CH * sizeof(float), stream);
    hipMemsetAsync(deg, 0, (size_t)N_NODES * sizeof(int), stream);

    k_deg<<<(N_EDGES + 255) / 256, 256, 0, stream>>>(rowv, deg);
    k_dinv<<<(N_NODES + 255) / 256, 256, 0, stream>>>(deg, dinv);
    k_scatter<<<N_EDGES / 4, 256, 0, stream>>>(rowv, colv, dinv, x, out);
    k_gemm<<<(N_NODES + TR - 1) / TR, 256, 0, stream>>>(out, W);
}

// Round 2
// 375.078 us; speedup vs baseline: 2.1346x; 2.1346x over previous
//
#include <hip/hip_runtime.h>

#define N_NODES 50000
#define N_EDGES 800000
#define CH 128
#define TR 32   // rows per GEMM block

// ---- degree count: one thread per edge, atomic int add ----
__global__ __launch_bounds__(256) void k_deg(const int* __restrict__ rowv,
                                             int* __restrict__ deg) {
    int e = blockIdx.x * 256 + threadIdx.x;
    if (e < N_EDGES) atomicAdd(&deg[rowv[e]], 1);
}

// ---- single-block scan: deg -> row_ptr (exclusive), cursor copy, dinv ----
__global__ __launch_bounds__(1024) void k_scan(const int* __restrict__ deg,
                                               int* __restrict__ row_ptr,
                                               int* __restrict__ cursor,
                                               float* __restrict__ dinv) {
    const int C = (N_NODES + 1023) / 1024;   // 49 elems/thread
    int t = threadIdx.x;
    int lo = t * C, hi = lo + C; if (hi > N_NODES) hi = N_NODES; if (lo > N_NODES) lo = N_NODES;

    int s = 0;
    for (int i = lo; i < hi; ++i) s += deg[i];

    // inclusive scan of per-thread sums across 1024 threads (16 waves)
    int lane = t & 63, wv = t >> 6;
    int v = s;
    #pragma unroll
    for (int d = 1; d < 64; d <<= 1) {
        int u = __shfl_up(v, d, 64);
        if (lane >= d) v += u;
    }
    __shared__ int wsum[16];
    if (lane == 63) wsum[wv] = v;
    __syncthreads();
    if (t < 16) {
        int w = wsum[t];
        #pragma unroll
        for (int d = 1; d < 16; d <<= 1) {
            int u = __shfl_up(w, d, 16);
            if (t >= d) w += u;
        }
        wsum[t] = w;   // inclusive wave sums
    }
    __syncthreads();
    int waveoff = (wv == 0) ? 0 : wsum[wv - 1];
    int run = waveoff + v - s;     // exclusive prefix for this thread's range
    for (int i = lo; i < hi; ++i) {
        int d = deg[i];
        row_ptr[i] = run;
        cursor[i]  = run;
        dinv[i] = rsqrtf((float)(d > 0 ? d : 1));
        run += d;
    }
    if (t == 1023) row_ptr[N_NODES] = waveoff + v;   // total = N_EDGES
}

// ---- counting-sort edges into CSR ----
__global__ __launch_bounds__(256) void k_fill(const int* __restrict__ rowv,
                                              const int* __restrict__ colv,
                                              int* __restrict__ cursor,
                                              int* __restrict__ csr_col) {
    int e = blockIdx.x * 256 + threadIdx.x;
    if (e < N_EDGES) {
        int pos = atomicAdd(&cursor[rowv[e]], 1);
        csr_col[pos] = colv[e];
    }
}

// ---- per-node gather-reduce: one wave per node, 2 channels/lane ----
__global__ __launch_bounds__(256) void k_agg(const int* __restrict__ row_ptr,
                                             const int* __restrict__ csr_col,
                                             const float* __restrict__ dinv,
                                             const float* __restrict__ x,
                                             float* __restrict__ agg) {
    int gid = blockIdx.x * 256 + threadIdx.x;
    int n = gid >> 6;
    int lane = threadIdx.x & 63;
    if (n >= N_NODES) return;
    int j = row_ptr[n], end = row_ptr[n + 1];
    const float2* __restrict__ x2 = (const float2*)x;
    float ax = 0.f, ay = 0.f;
    for (; j + 4 <= end; j += 4) {       // 4 independent gathers in flight
        int c0 = csr_col[j], c1 = csr_col[j + 1], c2 = csr_col[j + 2], c3 = csr_col[j + 3];
        float w0 = dinv[c0], w1 = dinv[c1], w2 = dinv[c2], w3 = dinv[c3];
        float2 v0 = x2[c0 * 64 + lane];
        float2 v1 = x2[c1 * 64 + lane];
        float2 v2 = x2[c2 * 64 + lane];
        float2 v3 = x2[c3 * 64 + lane];
        ax = fmaf(v0.x, w0, ax); ay = fmaf(v0.y, w0, ay);
        ax = fmaf(v1.x, w1, ax); ay = fmaf(v1.y, w1, ay);
        ax = fmaf(v2.x, w2, ax); ay = fmaf(v2.y, w2, ay);
        ax = fmaf(v3.x, w3, ax); ay = fmaf(v3.y, w3, ay);
    }
    for (; j < end; ++j) {
        int c = csr_col[j];
        float w = dinv[c];
        float2 v = x2[c * 64 + lane];
        ax = fmaf(v.x, w, ax); ay = fmaf(v.y, w, ay);
    }
    float dr = dinv[n];
    ((float2*)agg)[n * 64 + lane] = make_float2(ax * dr, ay * dr);
}

// ---- in-place GEMM: io (N x 128, holds agg) -> io = io @ W (128 x 128) ----
__global__ __launch_bounds__(256) void k_gemm(float* __restrict__ io,
                                              const float* __restrict__ W) {
    __shared__ float sW[CH * CH];   // 64 KB
    __shared__ float sA[TR * CH];   // 16 KB
    int t = threadIdx.x;

    const float4* W4 = (const float4*)W;
    float4* sW4 = (float4*)sW;
    #pragma unroll 4
    for (int i = t; i < CH * CH / 4; i += 256) sW4[i] = W4[i];

    int row0 = blockIdx.x * TR;
    int rows = N_NODES - row0; if (rows > TR) rows = TR;
    float4* sA4 = (float4*)sA;
    const float4* A4 = (const float4*)(io + (size_t)row0 * CH);
    for (int i = t; i < TR * CH / 4; i += 256) {
        int r = i >> 5;  // 32 float4 per row
        sA4[i] = (r < rows) ? A4[i] : make_float4(0.f, 0.f, 0.f, 0.f);
    }
    __syncthreads();

    int r0 = (t >> 5) * 4;
    int c0 = (t & 31) * 4;
    float acc[4][4] = {};
    for (int k = 0; k < CH; ++k) {
        float4 b = *(const float4*)&sW[k * CH + c0];
        #pragma unroll
        for (int i = 0; i < 4; ++i) {
            float a = sA[(r0 + i) * CH + k];
            acc[i][0] = fmaf(a, b.x, acc[i][0]);
            acc[i][1] = fmaf(a, b.y, acc[i][1]);
            acc[i][2] = fmaf(a, b.z, acc[i][2]);
            acc[i][3] = fmaf(a, b.w, acc[i][3]);
        }
    }
    #pragma unroll
    for (int i = 0; i < 4; ++i) {
        if (r0 + i < rows) {
            *(float4*)(io + (size_t)(row0 + r0 + i) * CH + c0) =
                make_float4(acc[i][0], acc[i][1], acc[i][2], acc[i][3]);
        }
    }
}

extern "C" void kernel_launch(void* const* d_in, const int* in_sizes, int n_in,
                              void* d_out, int out_size, void* d_ws, size_t ws_size,
                              hipStream_t stream) {
    const float* x = (const float*)d_in[0];
    const float* W = (const float*)d_in[1];
    const int* edge = (const int*)d_in[2];
    const int* rowv = edge;            // edge_index[0][:]
    const int* colv = edge + N_EDGES;  // edge_index[1][:]
    float* out = (float*)d_out;

    // workspace layout (ints unless noted): deg | row_ptr[N+1] | cursor | dinv(float) | csr_col
    int*   deg     = (int*)d_ws;
    int*   row_ptr = deg + N_NODES;
    int*   cursor  = row_ptr + N_NODES + 1;
    float* dinv    = (float*)(cursor + N_NODES);
    int*   csr_col = (int*)(dinv + N_NODES);

    hipMemsetAsync(deg, 0, (size_t)N_NODES * sizeof(int), stream);

    k_deg <<<(N_EDGES + 255) / 256, 256, 0, stream>>>(rowv, deg);
    k_scan<<<1, 1024, 0, stream>>>(deg, row_ptr, cursor, dinv);
    k_fill<<<(N_EDGES + 255) / 256, 256, 0, stream>>>(rowv, colv, cursor, csr_col);
    k_agg <<<(N_NODES * 64 + 255) / 256, 256, 0, stream>>>(row_ptr, csr_col, dinv, x, out);
    k_gemm<<<(N_NODES + TR - 1) / TR, 256, 0, stream>>>(out, W);
}

// Round 3
// 256.793 us; speedup vs baseline: 3.1178x; 1.4606x over previous
//
#include <hip/hip_runtime.h>

#define N_NODES 50000
#define N_EDGES 800000
#define CH 128
#define TR 32    // rows per GEMM block
#define NB 196   // scan blocks: 196*256 = 50176 >= N_NODES

// ---- degree count: one thread per edge, atomic int add ----
__global__ __launch_bounds__(256) void k_deg(const int* __restrict__ rowv,
                                             int* __restrict__ deg) {
    int e = blockIdx.x * 256 + threadIdx.x;
    if (e < N_EDGES) atomicAdd(&deg[rowv[e]], 1);
}

// ---- scan phase A: per-block sum of deg ----
__global__ __launch_bounds__(256) void k_bsum(const int* __restrict__ deg,
                                              int* __restrict__ bsum) {
    int i = blockIdx.x * 256 + threadIdx.x;
    int d = (i < N_NODES) ? deg[i] : 0;
    #pragma unroll
    for (int o = 32; o > 0; o >>= 1) d += __shfl_down(d, o, 64);
    __shared__ int ws[4];
    int lane = threadIdx.x & 63, wv = threadIdx.x >> 6;
    if (lane == 0) ws[wv] = d;
    __syncthreads();
    if (threadIdx.x == 0) bsum[blockIdx.x] = ws[0] + ws[1] + ws[2] + ws[3];
}

// ---- scan phase B: single block exclusive-scans the NB block sums ----
__global__ __launch_bounds__(256) void k_bscan(const int* __restrict__ bsum,
                                               int* __restrict__ boff) {
    int t = threadIdx.x;
    int v = (t < NB) ? bsum[t] : 0;
    int lane = t & 63, wv = t >> 6;
    int inc = v;
    #pragma unroll
    for (int d = 1; d < 64; d <<= 1) {
        int u = __shfl_up(inc, d, 64);
        if (lane >= d) inc += u;
    }
    __shared__ int ws[4];
    if (lane == 63) ws[wv] = inc;
    __syncthreads();
    int off = 0;
    for (int w = 0; w < wv; ++w) off += ws[w];
    if (t < NB) boff[t] = off + inc - v;   // exclusive prefix
}

// ---- scan phase C: intra-block scan + block offset -> row_ptr/cursor/dinv ----
__global__ __launch_bounds__(256) void k_rowptr(const int* __restrict__ deg,
                                                const int* __restrict__ boff,
                                                int* __restrict__ row_ptr,
                                                int* __restrict__ cursor,
                                                float* __restrict__ dinv) {
    int i = blockIdx.x * 256 + threadIdx.x;
    int d = (i < N_NODES) ? deg[i] : 0;
    int lane = threadIdx.x & 63, wv = threadIdx.x >> 6;
    int inc = d;
    #pragma unroll
    for (int s = 1; s < 64; s <<= 1) {
        int u = __shfl_up(inc, s, 64);
        if (lane >= s) inc += u;
    }
    __shared__ int ws[4];
    if (lane == 63) ws[wv] = inc;
    __syncthreads();
    int off = boff[blockIdx.x];
    for (int w = 0; w < wv; ++w) off += ws[w];
    int pos = off + inc - d;               // exclusive prefix for node i
    if (i < N_NODES) {
        row_ptr[i] = pos;
        cursor[i]  = pos;
        dinv[i] = rsqrtf((float)(d > 0 ? d : 1));
    }
    if (blockIdx.x == 0 && threadIdx.x == 0) row_ptr[N_NODES] = N_EDGES;
}

// ---- counting-sort edges into CSR ----
__global__ __launch_bounds__(256) void k_fill(const int* __restrict__ rowv,
                                              const int* __restrict__ colv,
                                              int* __restrict__ cursor,
                                              int* __restrict__ csr_col) {
    int e = blockIdx.x * 256 + threadIdx.x;
    if (e < N_EDGES) {
        int pos = atomicAdd(&cursor[rowv[e]], 1);
        csr_col[pos] = colv[e];
    }
}

// ---- per-node gather-reduce: one wave per node, 2 channels/lane ----
__global__ __launch_bounds__(256) void k_agg(const int* __restrict__ row_ptr,
                                             const int* __restrict__ csr_col,
                                             const float* __restrict__ dinv,
                                             const float* __restrict__ x,
                                             float* __restrict__ agg) {
    int gid = blockIdx.x * 256 + threadIdx.x;
    int n = gid >> 6;
    int lane = threadIdx.x & 63;
    if (n >= N_NODES) return;
    int j = row_ptr[n], end = row_ptr[n + 1];
    const float2* __restrict__ x2 = (const float2*)x;
    float ax = 0.f, ay = 0.f;
    for (; j + 4 <= end; j += 4) {       // 4 independent gathers in flight
        int c0 = csr_col[j], c1 = csr_col[j + 1], c2 = csr_col[j + 2], c3 = csr_col[j + 3];
        float w0 = dinv[c0], w1 = dinv[c1], w2 = dinv[c2], w3 = dinv[c3];
        float2 v0 = x2[c0 * 64 + lane];
        float2 v1 = x2[c1 * 64 + lane];
        float2 v2 = x2[c2 * 64 + lane];
        float2 v3 = x2[c3 * 64 + lane];
        ax = fmaf(v0.x, w0, ax); ay = fmaf(v0.y, w0, ay);
        ax = fmaf(v1.x, w1, ax); ay = fmaf(v1.y, w1, ay);
        ax = fmaf(v2.x, w2, ax); ay = fmaf(v2.y, w2, ay);
        ax = fmaf(v3.x, w3, ax); ay = fmaf(v3.y, w3, ay);
    }
    for (; j < end; ++j) {
        int c = csr_col[j];
        float w = dinv[c];
        float2 v = x2[c * 64 + lane];
        ax = fmaf(v.x, w, ax); ay = fmaf(v.y, w, ay);
    }
    float dr = dinv[n];
    ((float2*)agg)[n * 64 + lane] = make_float2(ax * dr, ay * dr);
}

// ---- in-place GEMM: io (N x 128, holds agg) -> io = io @ W (128 x 128) ----
__global__ __launch_bounds__(256) void k_gemm(float* __restrict__ io,
                                              const float* __restrict__ W) {
    __shared__ float sW[CH * CH];   // 64 KB
    __shared__ float sA[TR * CH];   // 16 KB
    int t = threadIdx.x;

    const float4* W4 = (const float4*)W;
    float4* sW4 = (float4*)sW;
    #pragma unroll 4
    for (int i = t; i < CH * CH / 4; i += 256) sW4[i] = W4[i];

    int row0 = blockIdx.x * TR;
    int rows = N_NODES - row0; if (rows > TR) rows = TR;
    float4* sA4 = (float4*)sA;
    const float4* A4 = (const float4*)(io + (size_t)row0 * CH);
    for (int i = t; i < TR * CH / 4; i += 256) {
        int r = i >> 5;  // 32 float4 per row
        sA4[i] = (r < rows) ? A4[i] : make_float4(0.f, 0.f, 0.f, 0.f);
    }
    __syncthreads();

    int r0 = (t >> 5) * 4;
    int c0 = (t & 31) * 4;
    float acc[4][4] = {};
    for (int k = 0; k < CH; ++k) {
        float4 b = *(const float4*)&sW[k * CH + c0];
        #pragma unroll
        for (int i = 0; i < 4; ++i) {
            float a = sA[(r0 + i) * CH + k];
            acc[i][0] = fmaf(a, b.x, acc[i][0]);
            acc[i][1] = fmaf(a, b.y, acc[i][1]);
            acc[i][2] = fmaf(a, b.z, acc[i][2]);
            acc[i][3] = fmaf(a, b.w, acc[i][3]);
        }
    }
    #pragma unroll
    for (int i = 0; i < 4; ++i) {
        if (r0 + i < rows) {
            *(float4*)(io + (size_t)(row0 + r0 + i) * CH + c0) =
                make_float4(acc[i][0], acc[i][1], acc[i][2], acc[i][3]);
        }
    }
}

extern "C" void kernel_launch(void* const* d_in, const int* in_sizes, int n_in,
                              void* d_out, int out_size, void* d_ws, size_t ws_size,
                              hipStream_t stream) {
    const float* x = (const float*)d_in[0];
    const float* W = (const float*)d_in[1];
    const int* edge = (const int*)d_in[2];
    const int* rowv = edge;            // edge_index[0][:]
    const int* colv = edge + N_EDGES;  // edge_index[1][:]
    float* out = (float*)d_out;

    // ws layout (ints unless noted): deg | row_ptr[N+1] | cursor | dinv(f32) | csr_col | bsum | boff
    int*   deg     = (int*)d_ws;
    int*   row_ptr = deg + N_NODES;
    int*   cursor  = row_ptr + N_NODES + 1;
    float* dinv    = (float*)(cursor + N_NODES);
    int*   csr_col = (int*)(dinv + N_NODES);
    int*   bsum    = csr_col + N_EDGES;
    int*   boff    = bsum + NB;

    hipMemsetAsync(deg, 0, (size_t)N_NODES * sizeof(int), stream);

    k_deg   <<<(N_EDGES + 255) / 256, 256, 0, stream>>>(rowv, deg);
    k_bsum  <<<NB, 256, 0, stream>>>(deg, bsum);
    k_bscan <<<1, 256, 0, stream>>>(bsum, boff);
    k_rowptr<<<NB, 256, 0, stream>>>(deg, boff, row_ptr, cursor, dinv);
    k_fill  <<<(N_EDGES + 255) / 256, 256, 0, stream>>>(rowv, colv, cursor, csr_col);
    k_agg   <<<(N_NODES * 64 + 255) / 256, 256, 0, stream>>>(row_ptr, csr_col, dinv, x, out);
    k_gemm  <<<(N_NODES + TR - 1) / TR, 256, 0, stream>>>(out, W);
}